// Round 13
// baseline (506.922 us; speedup 1.0000x reference)
//
#include <hip/hip_runtime.h>
#include <hip/hip_bf16.h>

typedef __hip_bfloat16 bf16;
typedef unsigned short u16;
typedef unsigned int u32;
typedef __attribute__((ext_vector_type(8))) short bf16x8;
typedef __attribute__((ext_vector_type(4))) float f32x4;
typedef __attribute__((ext_vector_type(2))) float f32x2;

#define NN 100000
#define NE 1600000
#define NG 64
#define NBKT 196            // buckets = dst >> 9
#define EPB 4096            // edges per partition block
#define NBLK ((NE + EPB - 1) / EPB)  // 391

// adaptive float load: isbf=1 -> buffer is bf16, else float32
__device__ __forceinline__ float ldf(const void* __restrict__ p, int i, int isbf) {
    return isbf ? __bfloat162float(((const bf16*)p)[i]) : ((const float*)p)[i];
}

// adaptive index load: is64=1 -> int64 little-endian (hi word 0), else int32
__device__ __forceinline__ int ld_idx(const int* __restrict__ p, int i, int is64) {
    return is64 ? p[2 * i] : p[i];
}

// f32 -> bf16 bits, round-to-nearest-even
__device__ __forceinline__ u16 f2bu(float f) {
    u32 u = __float_as_uint(f);
    u32 r = u + 0x7fffu + ((u >> 16) & 1u);
    return (u16)(r >> 16);
}
// bf16 bits -> f32
__device__ __forceinline__ float blo(u32 u) { return __uint_as_float(u << 16); }
__device__ __forceinline__ float bhi(u32 u) { return __uint_as_float(u & 0xffff0000u); }

// ---- detect dtypes: flags[0] ei int64, flags[1] batch int64, flags[2] floats bf16 ----
__global__ void k_detect(const int* __restrict__ ei, const int* __restrict__ bat,
                         const u16* __restrict__ xw, int* __restrict__ flags) {
    __shared__ int anyE, anyB, cntF;
    if (threadIdx.x == 0) { anyE = 0; anyB = 0; cntF = 0; }
    __syncthreads();
    int t = threadIdx.x;  // 256 threads
    int accE = 0, accB = 0;
#pragma unroll
    for (int i = 0; i < 8; i++) {
        int si = t * 8 + i;  // 2048 samples over odd int32 words of ei
        long long pe = ((long long)si * (2LL * NE)) / 2048;
        int ie = ((int)pe) | 1;
        if (ie < 2 * NE) accE |= ei[ie];
    }
    {
        int ib = (int)(((long long)t * NN) / 256) | 1;
        if (ib < NN) accB |= bat[ib];
    }
    if (accE) atomicOr(&anyE, 1);
    if (accB) atomicOr(&anyB, 1);
    {
        u16 w = xw[2 * t];
        int hb = (w >> 8) & 0x7F;
        if (hb >= 0x3B && hb <= 0x41) atomicAdd(&cntF, 1);
    }
    __syncthreads();
    if (threadIdx.x == 0) {
        flags[0] = anyE ? 0 : 1;
        flags[1] = anyB ? 0 : 1;
        flags[2] = (cntF > 128) ? 1 : 0;
    }
}

// ---- CSR p1: per-block bucket histograms, transposed write bhistT[bucket][blk] ----
__global__ void k_p1hist(const int* __restrict__ ei, const int* __restrict__ flags,
                         int* __restrict__ bhistT) {
    __shared__ int lh[NBKT];
    int t = threadIdx.x;  // 512
    if (t < NBKT) lh[t] = 0;
    __syncthreads();
    int is64 = flags[0];
    int base = blockIdx.x * EPB;
#pragma unroll
    for (int i = 0; i < EPB / 512; i++) {
        int e = base + i * 512 + t;
        if (e < NE) {
            int di = ld_idx(ei, NE + e, is64);
            atomicAdd(&lh[di >> 9], 1);
        }
    }
    __syncthreads();
    if (t < NBKT) bhistT[t * NBLK + blockIdx.x] = lh[t];
}

// ---- CSR p2a: per-bucket scan over blocks (196 blocks, coalesced columns) ----
__global__ void k_p2a(const int* __restrict__ bhistT, int* __restrict__ boffT,
                      int* __restrict__ btot) {
    __shared__ int sh[512];
    int b = blockIdx.x, t = threadIdx.x;  // 512 threads
    int v = (t < NBLK) ? bhistT[b * NBLK + t] : 0;
    sh[t] = v;
    __syncthreads();
#pragma unroll
    for (int off = 1; off < 512; off <<= 1) {
        int y = (t >= off) ? sh[t - off] : 0;
        __syncthreads();
        sh[t] += y;
        __syncthreads();
    }
    if (t < NBLK) boffT[b * NBLK + t] = sh[t] - v;  // bucket-local exclusive prefix
    if (t == 511) btot[b] = sh[511];
}

// ---- CSR p2b: scan bucket totals -> bucket bases ----
__global__ void k_p2b(const int* __restrict__ btot, int* __restrict__ bbase) {
    __shared__ int sh[256];
    int t = threadIdx.x;  // 256 threads
    int v = (t < NBKT) ? btot[t] : 0;
    sh[t] = v;
    __syncthreads();
#pragma unroll
    for (int off = 1; off < 256; off <<= 1) {
        int y = (t >= off) ? sh[t - off] : 0;
        __syncthreads();
        sh[t] += y;
        __syncthreads();
    }
    if (t < NBKT) bbase[t] = sh[t] - v;
    if (t == 255) bbase[NBKT] = sh[255];  // = NE
}

// ---- CSR p3: partition edges into bucket-contiguous packed (src<<9 | dst&511) ----
__global__ void k_p3part(const int* __restrict__ ei, const int* __restrict__ flags,
                         const int* __restrict__ boffT, const int* __restrict__ bbase,
                         u32* __restrict__ pairs) {
    __shared__ int loff[NBKT];
    int t = threadIdx.x;  // 512
    if (t < NBKT) loff[t] = bbase[t] + boffT[t * NBLK + blockIdx.x];
    __syncthreads();
    int is64 = flags[0];
    int base = blockIdx.x * EPB;
#pragma unroll
    for (int i = 0; i < EPB / 512; i++) {
        int e = base + i * 512 + t;
        if (e < NE) {
            int sj = ld_idx(ei, e, is64);
            int di = ld_idx(ei, NE + e, is64);
            int pos = atomicAdd(&loff[di >> 9], 1);
            pairs[pos] = ((u32)sj << 9) | (u32)(di & 511);
        }
    }
}

// ---- CSR p4: per-bucket counting sort -> rowptr + es (one block per bucket) ----
__global__ void k_p4sort(const u32* __restrict__ pairs, const int* __restrict__ bbase,
                         int* __restrict__ rowptr, int* __restrict__ es) {
    __shared__ int lcnt[512], pfx[512];
    int b = blockIdx.x, t = threadIdx.x;  // 512 threads
    int bb = bbase[b];
    int bend = bbase[b + 1];
    int n0 = b << 9;
    lcnt[t] = 0;
    __syncthreads();
    for (int p = bb + t; p < bend; p += 512)
        atomicAdd(&lcnt[pairs[p] & 511u], 1);
    __syncthreads();
    int v = lcnt[t];
    pfx[t] = v;
    __syncthreads();
#pragma unroll
    for (int off = 1; off < 512; off <<= 1) {
        int y = (t >= off) ? pfx[t - off] : 0;
        __syncthreads();
        pfx[t] += y;
        __syncthreads();
    }
    int start = bb + pfx[t] - v;  // exclusive
    int n = n0 + t;
    if (n < NN) rowptr[n] = start;
    lcnt[t] = start;  // running placement counter
    if (b == NBKT - 1 && t == 0) rowptr[NN] = NE;
    __syncthreads();
    for (int p = bb + t; p < bend; p += 512) {
        u32 pr = pairs[p];
        int pos = atomicAdd(&lcnt[pr & 511u], 1);
        es[pos] = (int)(pr >> 9);
    }
}

// ---- layer1 K/V only: x[N,3] @ W[3,64]; K fp8-e4m3, V bf16; kv1m[n]{64B k8|128B v} ----
__global__ void k_kv1(const void* __restrict__ x,
                      const void* __restrict__ Wk, const void* __restrict__ bk,
                      const void* __restrict__ Wv, const void* __restrict__ bv,
                      const int* __restrict__ flags, u16* __restrict__ kv1m) {
    int idx = blockIdx.x * blockDim.x + threadIdx.x;
    if (idx >= NN * 64) return;
    int fb = flags[2];
    int n = idx >> 6, d = idx & 63;
    float x0 = ldf(x, n * 3 + 0, fb);
    float x1 = ldf(x, n * 3 + 1, fb);
    float x2 = ldf(x, n * 3 + 2, fb);
    float kf = x0 * ldf(Wk, d, fb) + x1 * ldf(Wk, 64 + d, fb) + x2 * ldf(Wk, 128 + d, fb) + ldf(bk, d, fb);
    float vf = x0 * ldf(Wv, d, fb) + x1 * ldf(Wv, 64 + d, fb) + x2 * ldf(Wv, 128 + d, fb) + ldf(bv, d, fb);
    // k fp8: pair adjacent dims across adjacent lanes (same node: waves are node-aligned)
    float knb = __shfl_xor(kf, 1, 64);
    if (!(d & 1)) {
        int packed = __builtin_amdgcn_cvt_pk_fp8_f32(kf, knb, 0, false);
        kv1m[(size_t)n * 96 + (d >> 1)] = (u16)packed;
    }
    kv1m[(size_t)n * 96 + 32 + d] = f2bu(vf);
}

// ---- fused attention L1 (HD=64): q,s computed in-register from x; no-max softmax,
// 4 edges/wave, 16 lanes/edge, fp8 k (4B/lane) + bf16 v (8B/lane), depth-3 pipeline ----
__global__ void k_attn1(const int* __restrict__ rowptr, const int* __restrict__ es,
                        const void* __restrict__ x,
                        const void* __restrict__ Wq, const void* __restrict__ bq,
                        const void* __restrict__ Ws, const void* __restrict__ bs,
                        const int* __restrict__ flags,
                        const u16* __restrict__ kv1m, u16* __restrict__ h1b) {
    int w = (blockIdx.x * blockDim.x + threadIdx.x) >> 6;
    if (w >= NN) return;
    int lane = threadIdx.x & 63;
    int g = lane >> 4, hl = lane & 15;  // edge-group, lane-in-group (dims 4hl..4hl+3)
    int fb = flags[2];
    float x0 = ldf(x, w * 3 + 0, fb);
    float x1 = ldf(x, w * 3 + 1, fb);
    float x2 = ldf(x, w * 3 + 2, fb);
    const float scale = 0.17677669529663687f;  // 1/sqrt(32)
    int d0 = 4 * hl;
    float qs0 = (x0 * ldf(Wq, d0 + 0, fb) + x1 * ldf(Wq, 64 + d0 + 0, fb) + x2 * ldf(Wq, 128 + d0 + 0, fb) + ldf(bq, d0 + 0, fb)) * scale;
    float qs1 = (x0 * ldf(Wq, d0 + 1, fb) + x1 * ldf(Wq, 64 + d0 + 1, fb) + x2 * ldf(Wq, 128 + d0 + 1, fb) + ldf(bq, d0 + 1, fb)) * scale;
    float qs2 = (x0 * ldf(Wq, d0 + 2, fb) + x1 * ldf(Wq, 64 + d0 + 2, fb) + x2 * ldf(Wq, 128 + d0 + 2, fb) + ldf(bq, d0 + 2, fb)) * scale;
    float qs3 = (x0 * ldf(Wq, d0 + 3, fb) + x1 * ldf(Wq, 64 + d0 + 3, fb) + x2 * ldf(Wq, 128 + d0 + 3, fb) + ldf(bq, d0 + 3, fb)) * scale;
    float l = 0.0f, o0 = 0.0f, o1 = 0.0f, o2 = 0.0f, o3 = 0.0f;
    int beg = rowptr[w], end = rowptr[w + 1];
    int iters = (end - beg + 3) >> 2;
#define PROC1(ku, vu, vld) { \
    f32x2 k01 = __builtin_amdgcn_cvt_pk_f32_fp8((int)ku, false); \
    f32x2 k23 = __builtin_amdgcn_cvt_pk_f32_fp8((int)ku, true); \
    float t = qs0 * k01.x + qs1 * k01.y + qs2 * k23.x + qs3 * k23.y; \
    t += __shfl_xor(t, 4, 64); t += __shfl_xor(t, 2, 64); t += __shfl_xor(t, 1, 64); \
    float e = (vld) ? __expf(t) : 0.0f; \
    l += e; \
    o0 += e * blo(vu.x); o1 += e * bhi(vu.x); \
    o2 += e * blo(vu.y); o3 += e * bhi(vu.y); }
    if (iters > 0) {
        int pA = beg + g;
        int vA = pA < end; int sjA = es[vA ? pA : beg];
        u32 kA = *(const u32*)(kv1m + (size_t)sjA * 96 + hl * 2);
        uint2 uA = *(const uint2*)(kv1m + (size_t)sjA * 96 + 32 + hl * 4);
        int pB = pA + 4;
        int vB = pB < end; int sjB = es[vB ? pB : beg];
        u32 kB = *(const u32*)(kv1m + (size_t)sjB * 96 + hl * 2);
        uint2 uB = *(const uint2*)(kv1m + (size_t)sjB * 96 + 32 + hl * 4);
        int pC = pA + 8;
        int vC = pC < end; int sjC = es[vC ? pC : beg];
        u32 kC = *(const u32*)(kv1m + (size_t)sjC * 96 + hl * 2);
        uint2 uC = *(const uint2*)(kv1m + (size_t)sjC * 96 + 32 + hl * 4);
        for (int i = 0; i < iters; i += 3) {
            int pD = pA + 12;
            int vD = pD < end; int sjD = es[vD ? pD : beg];
            u32 kD = *(const u32*)(kv1m + (size_t)sjD * 96 + hl * 2);
            uint2 uD = *(const uint2*)(kv1m + (size_t)sjD * 96 + 32 + hl * 4);
            PROC1(kA, uA, vA);
            int pE = pA + 16;
            int vE = pE < end; int sjE = es[vE ? pE : beg];
            u32 kE = *(const u32*)(kv1m + (size_t)sjE * 96 + hl * 2);
            uint2 uE = *(const uint2*)(kv1m + (size_t)sjE * 96 + 32 + hl * 4);
            PROC1(kB, uB, vB);
            int pF = pA + 20;
            int vF = pF < end; int sjF = es[vF ? pF : beg];
            u32 kF = *(const u32*)(kv1m + (size_t)sjF * 96 + hl * 2);
            uint2 uF = *(const uint2*)(kv1m + (size_t)sjF * 96 + 32 + hl * 4);
            PROC1(kC, uC, vC);
            pA = pD; vA = vD; kA = kD; uA = uD;
            pB = pE; vB = vE; kB = kE; uB = uE;
            pC = pF; vC = vF; kC = kF; uC = uF;
        }
    }
#undef PROC1
#pragma unroll
    for (int off = 16; off <= 32; off <<= 1) {
        l += __shfl_xor(l, off, 64);
        o0 += __shfl_xor(o0, off, 64);
        o1 += __shfl_xor(o1, off, 64);
        o2 += __shfl_xor(o2, off, 64);
        o3 += __shfl_xor(o3, off, 64);
    }
    if (g == 0) {
        float inv = 1.0f / (l + 1e-16f);
        float sv0 = x0 * ldf(Ws, d0 + 0, fb) + x1 * ldf(Ws, 64 + d0 + 0, fb) + x2 * ldf(Ws, 128 + d0 + 0, fb) + ldf(bs, d0 + 0, fb);
        float sv1 = x0 * ldf(Ws, d0 + 1, fb) + x1 * ldf(Ws, 64 + d0 + 1, fb) + x2 * ldf(Ws, 128 + d0 + 1, fb) + ldf(bs, d0 + 1, fb);
        float sv2 = x0 * ldf(Ws, d0 + 2, fb) + x1 * ldf(Ws, 64 + d0 + 2, fb) + x2 * ldf(Ws, 128 + d0 + 2, fb) + ldf(bs, d0 + 2, fb);
        float sv3 = x0 * ldf(Ws, d0 + 3, fb) + x1 * ldf(Ws, 64 + d0 + 3, fb) + x2 * ldf(Ws, 128 + d0 + 3, fb) + ldf(bs, d0 + 3, fb);
        uint2 r;
        r.x = (u32)f2bu(fmaxf(sv0 + o0 * inv, 0.0f)) | ((u32)f2bu(fmaxf(sv1 + o1 * inv, 0.0f)) << 16);
        r.y = (u32)f2bu(fmaxf(sv2 + o2 * inv, 0.0f)) | ((u32)f2bu(fmaxf(sv3 + o3 * inv, 0.0f)) << 16);
        ((uint2*)(h1b + (size_t)w * 64))[hl] = r;
    }
}

// ---- weight prep for layer2 GEMM: Wt[512][64] bf16, bias512 f32; also zeroes g ----
__global__ void k_wprep(const void* __restrict__ Wq, const void* __restrict__ bq,
                        const void* __restrict__ Wk, const void* __restrict__ bk,
                        const void* __restrict__ Wv, const void* __restrict__ bv,
                        const void* __restrict__ Ws, const void* __restrict__ bs,
                        const int* __restrict__ flags,
                        u16* __restrict__ Wt, float* __restrict__ bias,
                        float* __restrict__ g) {
    int idx = blockIdx.x * blockDim.x + threadIdx.x;
    if (idx >= 512 * 64) return;
    if (idx < NG * 128) g[idx] = 0.0f;
    int fb = flags[2];
    int n = idx >> 6, k = idx & 63;
    int mat = n >> 7, c = n & 127;
    const void* W = (mat == 0) ? Wq : (mat == 1) ? Wk : (mat == 2) ? Wv : Ws;
    Wt[n * 64 + k] = f2bu(ldf(W, k * 128 + c, fb));
    if (k == 0) {
        const void* B = (mat == 0) ? bq : (mat == 1) ? bk : (mat == 2) ? bv : bs;
        bias[n] = ldf(B, c, fb);
    }
}

// ---- layer2 QKVS via MFMA; Q bf16, K fp8-e4m3 + V bf16 packed kvm[n]{128B k8|256B v}, S bf16 ----
__global__ void k_gemm2(const u16* __restrict__ h1b, const u16* __restrict__ Wt,
                        const float* __restrict__ bias,
                        u16* __restrict__ q2b, u16* __restrict__ kvm,
                        u16* __restrict__ s2b) {
    int w = (blockIdx.x * blockDim.x + threadIdx.x) >> 6;
    if (w >= NN / 16) return;  // 6250 waves
    int lane = threadIdx.x & 63;
    int quad = lane >> 4, mr = lane & 15;
    int m0 = w * 16;
    const u16* arow = h1b + (size_t)(m0 + mr) * 64 + quad * 8;
    bf16x8 a0 = *(const bf16x8*)(arow);
    bf16x8 a1 = *(const bf16x8*)(arow + 32);
#pragma unroll 4
    for (int n0 = 0; n0 < 512; n0 += 16) {
        const u16* brow = Wt + (size_t)(n0 + mr) * 64 + quad * 8;
        bf16x8 b0 = *(const bf16x8*)(brow);
        bf16x8 b1 = *(const bf16x8*)(brow + 32);
        f32x4 acc = {0.f, 0.f, 0.f, 0.f};
        acc = __builtin_amdgcn_mfma_f32_16x16x32_bf16(a0, b0, acc, 0, 0, 0);
        acc = __builtin_amdgcn_mfma_f32_16x16x32_bf16(a1, b1, acc, 0, 0, 0);
        float bs = bias[n0 + mr];
        int mat = n0 >> 7;
        int c = (n0 & 127) + mr;
#pragma unroll
        for (int r = 0; r < 4; r++) {
            int row = m0 + quad * 4 + r;
            float val = acc[r] + bs;
            if (mat == 1) {
                // fp8 k: pack column pairs across adjacent lanes (same row)
                float nb = __shfl_xor(val, 1, 64);
                if (!(mr & 1)) {
                    int packed = __builtin_amdgcn_cvt_pk_fp8_f32(val, nb, 0, false);
                    *(u16*)((char*)kvm + (size_t)row * 384 + c) = (u16)packed;
                }
            } else if (mat == 0) {
                q2b[(size_t)row * 128 + c] = f2bu(val);
            } else if (mat == 2) {
                kvm[(size_t)row * 192 + 64 + c] = f2bu(val);
            } else {
                s2b[(size_t)row * 128 + c] = f2bu(val);
            }
        }
    }
}

// ---- fused attention L2 (HD=128): no-max softmax, 4 edges/wave, 16 lanes/edge,
// fp8 k (8B/lane) + bf16 v (16B/lane), depth-3 software pipeline; h2 out bf16 ----
__global__ void k_attn2(const int* __restrict__ rowptr, const int* __restrict__ es,
                        const u16* __restrict__ q2b, const u16* __restrict__ kvm,
                        const u16* __restrict__ s2b, u16* __restrict__ h2b) {
    int w = (blockIdx.x * blockDim.x + threadIdx.x) >> 6;
    if (w >= NN) return;
    int lane = threadIdx.x & 63;
    int g = lane >> 4, hl = lane & 15;  // dims 8hl..8hl+7
    const float scale = 0.125f;  // 1/sqrt(64)
    uint4 qu = ((const uint4*)(q2b + (size_t)w * 128))[hl];
    float qs[8];
    qs[0] = blo(qu.x) * scale; qs[1] = bhi(qu.x) * scale;
    qs[2] = blo(qu.y) * scale; qs[3] = bhi(qu.y) * scale;
    qs[4] = blo(qu.z) * scale; qs[5] = bhi(qu.z) * scale;
    qs[6] = blo(qu.w) * scale; qs[7] = bhi(qu.w) * scale;
    float l = 0.0f;
    float o[8] = {0.f, 0.f, 0.f, 0.f, 0.f, 0.f, 0.f, 0.f};
    int beg = rowptr[w], end = rowptr[w + 1];
    int iters = (end - beg + 3) >> 2;
#define PROC2(ku, vu, vld) { \
    f32x2 k01 = __builtin_amdgcn_cvt_pk_f32_fp8((int)ku.x, false); \
    f32x2 k23 = __builtin_amdgcn_cvt_pk_f32_fp8((int)ku.x, true); \
    f32x2 k45 = __builtin_amdgcn_cvt_pk_f32_fp8((int)ku.y, false); \
    f32x2 k67 = __builtin_amdgcn_cvt_pk_f32_fp8((int)ku.y, true); \
    float t = qs[0] * k01.x + qs[1] * k01.y + qs[2] * k23.x + qs[3] * k23.y \
            + qs[4] * k45.x + qs[5] * k45.y + qs[6] * k67.x + qs[7] * k67.y; \
    t += __shfl_xor(t, 4, 64); t += __shfl_xor(t, 2, 64); t += __shfl_xor(t, 1, 64); \
    float e = (vld) ? __expf(t) : 0.0f; \
    l += e; \
    o[0] += e * blo(vu.x); o[1] += e * bhi(vu.x); \
    o[2] += e * blo(vu.y); o[3] += e * bhi(vu.y); \
    o[4] += e * blo(vu.z); o[5] += e * bhi(vu.z); \
    o[6] += e * blo(vu.w); o[7] += e * bhi(vu.w); }
    if (iters > 0) {
        int pA = beg + g;
        int vA = pA < end; int sjA = es[vA ? pA : beg];
        uint2 kA = ((const uint2*)(kvm + (size_t)sjA * 192))[hl];
        uint4 uA = ((const uint4*)(kvm + (size_t)sjA * 192 + 64))[hl];
        int pB = pA + 4;
        int vB = pB < end; int sjB = es[vB ? pB : beg];
        uint2 kB = ((const uint2*)(kvm + (size_t)sjB * 192))[hl];
        uint4 uB = ((const uint4*)(kvm + (size_t)sjB * 192 + 64))[hl];
        int pC = pA + 8;
        int vC = pC < end; int sjC = es[vC ? pC : beg];
        uint2 kC = ((const uint2*)(kvm + (size_t)sjC * 192))[hl];
        uint4 uC = ((const uint4*)(kvm + (size_t)sjC * 192 + 64))[hl];
        for (int i = 0; i < iters; i += 3) {
            int pD = pA + 12;
            int vD = pD < end; int sjD = es[vD ? pD : beg];
            uint2 kD = ((const uint2*)(kvm + (size_t)sjD * 192))[hl];
            uint4 uD = ((const uint4*)(kvm + (size_t)sjD * 192 + 64))[hl];
            PROC2(kA, uA, vA);
            int pE = pA + 16;
            int vE = pE < end; int sjE = es[vE ? pE : beg];
            uint2 kE = ((const uint2*)(kvm + (size_t)sjE * 192))[hl];
            uint4 uE = ((const uint4*)(kvm + (size_t)sjE * 192 + 64))[hl];
            PROC2(kB, uB, vB);
            int pF = pA + 20;
            int vF = pF < end; int sjF = es[vF ? pF : beg];
            uint2 kF = ((const uint2*)(kvm + (size_t)sjF * 192))[hl];
            uint4 uF = ((const uint4*)(kvm + (size_t)sjF * 192 + 64))[hl];
            PROC2(kC, uC, vC);
            pA = pD; vA = vD; kA = kD; uA = uD;
            pB = pE; vB = vE; kB = kE; uB = uE;
            pC = pF; vC = vF; kC = kF; uC = uF;
        }
    }
#undef PROC2
#pragma unroll
    for (int off = 16; off <= 32; off <<= 1) {
        l += __shfl_xor(l, off, 64);
#pragma unroll
        for (int j = 0; j < 8; j++) o[j] += __shfl_xor(o[j], off, 64);
    }
    if (g == 0) {
        float inv = 1.0f / (l + 1e-16f);
        uint4 su = ((const uint4*)(s2b + (size_t)w * 128))[hl];
        uint4 r;
        r.x = (u32)f2bu(blo(su.x) + o[0] * inv) | ((u32)f2bu(bhi(su.x) + o[1] * inv) << 16);
        r.y = (u32)f2bu(blo(su.y) + o[2] * inv) | ((u32)f2bu(bhi(su.y) + o[3] * inv) << 16);
        r.z = (u32)f2bu(blo(su.z) + o[4] * inv) | ((u32)f2bu(bhi(su.z) + o[5] * inv) << 16);
        r.w = (u32)f2bu(blo(su.w) + o[6] * inv) | ((u32)f2bu(bhi(su.w) + o[7] * inv) << 16);
        ((uint4*)(h2b + (size_t)w * 128))[hl] = r;
    }
}

// ---- relu + global max pool over sorted batch (pre-reduced runs: ~0.8M atomics) ----
__global__ void k_pool(const u16* __restrict__ h2b, const int* __restrict__ batch,
                       const int* __restrict__ flags, float* __restrict__ g) {
    int idx = blockIdx.x * blockDim.x + threadIdx.x;
    if (idx >= (NN / 16) * 128) return;
    int is64 = flags[1];
    int d = idx & 127, ch = idx >> 7;
    int n0 = ch * 16;
    int curb = ld_idx(batch, n0, is64);
    float mx = 0.0f;  // relu floor
    for (int i = 0; i < 16; i++) {
        int n = n0 + i;
        int b = ld_idx(batch, n, is64);
        if (b != curb) {
            atomicMax((int*)&g[curb * 128 + d], __float_as_int(mx));
            mx = 0.0f;
            curb = b;
        }
        mx = fmaxf(mx, __uint_as_float(((u32)h2b[(size_t)n * 128 + d]) << 16));
    }
    atomicMax((int*)&g[curb * 128 + d], __float_as_int(mx));
}

// ---- MLP head: one block per graph; f32 outputs ----
__global__ void k_mlp(const float* __restrict__ g,
                      const void* __restrict__ W1, const void* __restrict__ b1,
                      const void* __restrict__ W2, const void* __restrict__ b2,
                      const void* __restrict__ W3, const void* __restrict__ b3,
                      const int* __restrict__ flags, float* __restrict__ out) {
    __shared__ float gr[128], lat[32], h2[128];
    int gid = blockIdx.x, t = threadIdx.x;  // 128 threads
    int fb = flags[2];
    gr[t] = g[gid * 128 + t];
    __syncthreads();
    if (t < 32) {
        float a = ldf(b1, t, fb);
        for (int k = 0; k < 128; k++) a += gr[k] * ldf(W1, k * 32 + t, fb);
        a = fmaxf(a, 0.0f);
        lat[t] = a;
        out[NG * 40 + gid * 32 + t] = a;
    }
    __syncthreads();
    {
        float a = ldf(b2, t, fb);
        for (int k = 0; k < 32; k++) a += lat[k] * ldf(W2, k * 128 + t, fb);
        h2[t] = fmaxf(a, 0.0f);
    }
    __syncthreads();
    if (t < 40) {
        float a = ldf(b3, t, fb);
        for (int k = 0; k < 128; k++) a += h2[k] * ldf(W3, k * 40 + t, fb);
        out[gid * 40 + t] = a;
    }
}

extern "C" void kernel_launch(void* const* d_in, const int* in_sizes, int n_in,
                              void* d_out, int out_size, void* d_ws, size_t ws_size,
                              hipStream_t stream) {
    const void* x     = d_in[0];
    const int*  ei    = (const int*)d_in[1];
    const int*  batch = (const int*)d_in[2];
    const void *Wq1 = d_in[3],  *bq1 = d_in[4];
    const void *Wk1 = d_in[5],  *bk1 = d_in[6];
    const void *Wv1 = d_in[7],  *bv1 = d_in[8];
    const void *Ws1 = d_in[9],  *bs1 = d_in[10];
    const void *Wq2 = d_in[11], *bq2 = d_in[12];
    const void *Wk2 = d_in[13], *bk2 = d_in[14];
    const void *Wv2 = d_in[15], *bv2 = d_in[16];
    const void *Ws2 = d_in[17], *bs2 = d_in[18];
    const void *W1  = d_in[19], *b1  = d_in[20];
    const void *W2  = d_in[21], *b2  = d_in[22];
    const void *W3  = d_in[23], *b3  = d_in[24];

    // ---- workspace layout ----
    float* ws = (float*)d_ws;
    float* g    = ws;                                   // [64,128] f32
    float* bias = g + NG * 128;                         // [512] f32
    u16* u16base = (u16*)(bias + 512);
    u16* kvm   = u16base;                               // [N,192] u16: 128B k-fp8 | 256B v-bf16
    u16* kv1m  = kvm + (size_t)NN * 192;                // [N,96]  u16: 64B k-fp8 | 128B v-bf16
    u16* h1b   = kv1m + (size_t)NN * 96;                // [N,64]  bf16
    u16* q2b   = h1b + (size_t)NN * 64;                 // [N,128] bf16
    u16* s2b   = q2b + (size_t)NN * 128;                // [N,128] bf16
    u16* h2b   = s2b + (size_t)NN * 128;                // [N,128] bf16
    u16* Wt    = h2b + (size_t)NN * 128;                // [512,64] bf16
    int* flags  = (int*)(Wt + 512 * 64);                // [8]
    int* rowptr = flags + 8;                            // [NN+1]
    int* bhistT = rowptr + NN + 1;                      // [NBKT*NBLK]
    int* boffT  = bhistT + NBKT * NBLK;                 // [NBKT*NBLK]
    int* btot   = boffT + NBKT * NBLK;                  // [NBKT]
    int* bbase  = btot + NBKT;                          // [NBKT+1]
    int* es     = bbase + NBKT + 1;                     // [NE]
    // pairs aliases kvm (dead-time disjoint: CSR build finishes before gemm2 writes kvm)
    u32* pairs = (u32*)kvm;                             // [NE] = 6.4 MB <= 38.4 MB

    float* out  = (float*)d_out;

    const int B = 256;
    k_detect<<<1, 256, 0, stream>>>(ei, batch, (const u16*)x, flags);
    // ---- CSR build: bucketed counting sort (no global atomics, fully parallel scan) ----
    k_p1hist<<<NBLK, 512, 0, stream>>>(ei, flags, bhistT);
    k_p2a<<<NBKT, 512, 0, stream>>>(bhistT, boffT, btot);
    k_p2b<<<1, 256, 0, stream>>>(btot, bbase);
    k_p3part<<<NBLK, 512, 0, stream>>>(ei, flags, boffT, bbase, pairs);
    k_p4sort<<<NBKT, 512, 0, stream>>>(pairs, bbase, rowptr, es);
    // ---- layer 1 (q,s computed inside attn1) ----
    k_kv1<<<(NN * 64 + B - 1) / B, B, 0, stream>>>(x, Wk1, bk1, Wv1, bv1, flags, kv1m);
    k_attn1<<<(NN * 64 + B - 1) / B, B, 0, stream>>>(rowptr, es, x, Wq1, bq1, Ws1, bs1,
                                                     flags, kv1m, h1b);
    // ---- layer 2 ----
    k_wprep<<<(512 * 64 + B - 1) / B, B, 0, stream>>>(Wq2, bq2, Wk2, bk2, Wv2, bv2, Ws2, bs2,
                                                      flags, Wt, bias, g);
    k_gemm2<<<(NN / 16 * 64 + B - 1) / B, B, 0, stream>>>(h1b, Wt, bias, q2b, kvm, s2b);
    k_attn2<<<(NN * 64 + B - 1) / B, B, 0, stream>>>(rowptr, es, q2b, kvm, s2b, h2b);
    // ---- pool + MLP ----
    k_pool<<<((NN / 16) * 128 + B - 1) / B, B, 0, stream>>>(h2b, batch, flags, g);
    k_mlp<<<NG, 128, 0, stream>>>(g, W1, b1, W2, b2, W3, b3, flags, out);
}

// Round 14
// 435.414 us; speedup vs baseline: 1.1642x; 1.1642x over previous
//
#include <hip/hip_runtime.h>
#include <hip/hip_bf16.h>

typedef __hip_bfloat16 bf16;
typedef unsigned short u16;
typedef unsigned int u32;
typedef __attribute__((ext_vector_type(8))) short bf16x8;
typedef __attribute__((ext_vector_type(4))) float f32x4;
typedef __attribute__((ext_vector_type(2))) float f32x2;

#define NN 100000
#define NE 1600000
#define NG 64
#define NBKT 196            // buckets = dst >> 9
#define EPB 4096            // edges per partition block
#define NBLK ((NE + EPB - 1) / EPB)  // 391

// adaptive float load: isbf=1 -> buffer is bf16, else float32
__device__ __forceinline__ float ldf(const void* __restrict__ p, int i, int isbf) {
    return isbf ? __bfloat162float(((const bf16*)p)[i]) : ((const float*)p)[i];
}

// adaptive index load: is64=1 -> int64 little-endian (hi word 0), else int32
__device__ __forceinline__ int ld_idx(const int* __restrict__ p, int i, int is64) {
    return is64 ? p[2 * i] : p[i];
}

// f32 -> bf16 bits, round-to-nearest-even
__device__ __forceinline__ u16 f2bu(float f) {
    u32 u = __float_as_uint(f);
    u32 r = u + 0x7fffu + ((u >> 16) & 1u);
    return (u16)(r >> 16);
}
// bf16 bits -> f32
__device__ __forceinline__ float blo(u32 u) { return __uint_as_float(u << 16); }
__device__ __forceinline__ float bhi(u32 u) { return __uint_as_float(u & 0xffff0000u); }

// ---- detect dtypes: flags[0] ei int64, flags[1] batch int64, flags[2] floats bf16 ----
__global__ void k_detect(const int* __restrict__ ei, const int* __restrict__ bat,
                         const u16* __restrict__ xw, int* __restrict__ flags) {
    __shared__ int anyE, anyB, cntF;
    if (threadIdx.x == 0) { anyE = 0; anyB = 0; cntF = 0; }
    __syncthreads();
    int t = threadIdx.x;  // 256 threads
    int accE = 0, accB = 0;
#pragma unroll
    for (int i = 0; i < 8; i++) {
        int si = t * 8 + i;  // 2048 samples over odd int32 words of ei
        long long pe = ((long long)si * (2LL * NE)) / 2048;
        int ie = ((int)pe) | 1;
        if (ie < 2 * NE) accE |= ei[ie];
    }
    {
        int ib = (int)(((long long)t * NN) / 256) | 1;
        if (ib < NN) accB |= bat[ib];
    }
    if (accE) atomicOr(&anyE, 1);
    if (accB) atomicOr(&anyB, 1);
    {
        u16 w = xw[2 * t];
        int hb = (w >> 8) & 0x7F;
        if (hb >= 0x3B && hb <= 0x41) atomicAdd(&cntF, 1);
    }
    __syncthreads();
    if (threadIdx.x == 0) {
        flags[0] = anyE ? 0 : 1;
        flags[1] = anyB ? 0 : 1;
        flags[2] = (cntF > 128) ? 1 : 0;
    }
}

// ---- CSR p1: per-block bucket histograms, transposed write bhistT[bucket][blk] ----
__global__ void k_p1hist(const int* __restrict__ ei, const int* __restrict__ flags,
                         int* __restrict__ bhistT) {
    __shared__ int lh[NBKT];
    int t = threadIdx.x;  // 512
    if (t < NBKT) lh[t] = 0;
    __syncthreads();
    int is64 = flags[0];
    int base = blockIdx.x * EPB;
#pragma unroll
    for (int i = 0; i < EPB / 512; i++) {
        int e = base + i * 512 + t;
        if (e < NE) {
            int di = ld_idx(ei, NE + e, is64);
            atomicAdd(&lh[di >> 9], 1);
        }
    }
    __syncthreads();
    if (t < NBKT) bhistT[t * NBLK + blockIdx.x] = lh[t];
}

// ---- CSR p2a: per-bucket scan over blocks (196 blocks, coalesced columns) ----
__global__ void k_p2a(const int* __restrict__ bhistT, int* __restrict__ boffT,
                      int* __restrict__ btot) {
    __shared__ int sh[512];
    int b = blockIdx.x, t = threadIdx.x;  // 512 threads
    int v = (t < NBLK) ? bhistT[b * NBLK + t] : 0;
    sh[t] = v;
    __syncthreads();
#pragma unroll
    for (int off = 1; off < 512; off <<= 1) {
        int y = (t >= off) ? sh[t - off] : 0;
        __syncthreads();
        sh[t] += y;
        __syncthreads();
    }
    if (t < NBLK) boffT[b * NBLK + t] = sh[t] - v;  // bucket-local exclusive prefix
    if (t == 511) btot[b] = sh[511];
}

// ---- CSR p2b: scan bucket totals -> bucket bases ----
__global__ void k_p2b(const int* __restrict__ btot, int* __restrict__ bbase) {
    __shared__ int sh[256];
    int t = threadIdx.x;  // 256 threads
    int v = (t < NBKT) ? btot[t] : 0;
    sh[t] = v;
    __syncthreads();
#pragma unroll
    for (int off = 1; off < 256; off <<= 1) {
        int y = (t >= off) ? sh[t - off] : 0;
        __syncthreads();
        sh[t] += y;
        __syncthreads();
    }
    if (t < NBKT) bbase[t] = sh[t] - v;
    if (t == 255) bbase[NBKT] = sh[255];  // = NE
}

// ---- CSR p3: partition edges into bucket-contiguous packed (src<<9 | dst&511) ----
__global__ void k_p3part(const int* __restrict__ ei, const int* __restrict__ flags,
                         const int* __restrict__ boffT, const int* __restrict__ bbase,
                         u32* __restrict__ pairs) {
    __shared__ int loff[NBKT];
    int t = threadIdx.x;  // 512
    if (t < NBKT) loff[t] = bbase[t] + boffT[t * NBLK + blockIdx.x];
    __syncthreads();
    int is64 = flags[0];
    int base = blockIdx.x * EPB;
#pragma unroll
    for (int i = 0; i < EPB / 512; i++) {
        int e = base + i * 512 + t;
        if (e < NE) {
            int sj = ld_idx(ei, e, is64);
            int di = ld_idx(ei, NE + e, is64);
            int pos = atomicAdd(&loff[di >> 9], 1);
            pairs[pos] = ((u32)sj << 9) | (u32)(di & 511);
        }
    }
}

// ---- CSR p4: per-bucket counting sort -> rowptr + es (one block per bucket) ----
__global__ void k_p4sort(const u32* __restrict__ pairs, const int* __restrict__ bbase,
                         int* __restrict__ rowptr, int* __restrict__ es) {
    __shared__ int lcnt[512], pfx[512];
    int b = blockIdx.x, t = threadIdx.x;  // 512 threads
    int bb = bbase[b];
    int bend = bbase[b + 1];
    int n0 = b << 9;
    lcnt[t] = 0;
    __syncthreads();
    for (int p = bb + t; p < bend; p += 512)
        atomicAdd(&lcnt[pairs[p] & 511u], 1);
    __syncthreads();
    int v = lcnt[t];
    pfx[t] = v;
    __syncthreads();
#pragma unroll
    for (int off = 1; off < 512; off <<= 1) {
        int y = (t >= off) ? pfx[t - off] : 0;
        __syncthreads();
        pfx[t] += y;
        __syncthreads();
    }
    int start = bb + pfx[t] - v;  // exclusive
    int n = n0 + t;
    if (n < NN) rowptr[n] = start;
    lcnt[t] = start;  // running placement counter
    if (b == NBKT - 1 && t == 0) rowptr[NN] = NE;
    __syncthreads();
    for (int p = bb + t; p < bend; p += 512) {
        u32 pr = pairs[p];
        int pos = atomicAdd(&lcnt[pr & 511u], 1);
        es[pos] = (int)(pr >> 9);
    }
}

// ---- layer1 Q/K/V/S: x[N,3] @ W[3,64]; Q,S,V bf16, K fp8; kv1m[n]{64B k8|128B v} ----
__global__ void k_qkvs1(const void* __restrict__ x,
                        const void* __restrict__ Wq, const void* __restrict__ bq,
                        const void* __restrict__ Wk, const void* __restrict__ bk,
                        const void* __restrict__ Wv, const void* __restrict__ bv,
                        const void* __restrict__ Ws, const void* __restrict__ bs,
                        const int* __restrict__ flags,
                        u16* __restrict__ q1b, u16* __restrict__ kv1m,
                        u16* __restrict__ s1b) {
    int idx = blockIdx.x * blockDim.x + threadIdx.x;
    if (idx >= NN * 64) return;
    int fb = flags[2];
    int n = idx >> 6, d = idx & 63;
    float x0 = ldf(x, n * 3 + 0, fb);
    float x1 = ldf(x, n * 3 + 1, fb);
    float x2 = ldf(x, n * 3 + 2, fb);
    q1b[idx] = f2bu(x0 * ldf(Wq, d, fb) + x1 * ldf(Wq, 64 + d, fb) + x2 * ldf(Wq, 128 + d, fb) + ldf(bq, d, fb));
    s1b[idx] = f2bu(x0 * ldf(Ws, d, fb) + x1 * ldf(Ws, 64 + d, fb) + x2 * ldf(Ws, 128 + d, fb) + ldf(bs, d, fb));
    float kf = x0 * ldf(Wk, d, fb) + x1 * ldf(Wk, 64 + d, fb) + x2 * ldf(Wk, 128 + d, fb) + ldf(bk, d, fb);
    float vf = x0 * ldf(Wv, d, fb) + x1 * ldf(Wv, 64 + d, fb) + x2 * ldf(Wv, 128 + d, fb) + ldf(bv, d, fb);
    // k fp8: pair adjacent dims across adjacent lanes (waves are node-aligned: lane = d)
    float knb = __shfl_xor(kf, 1, 64);
    if (!(d & 1)) {
        int packed = __builtin_amdgcn_cvt_pk_fp8_f32(kf, knb, 0, false);
        kv1m[(size_t)n * 96 + (d >> 1)] = (u16)packed;
    }
    kv1m[(size_t)n * 96 + 32 + d] = f2bu(vf);
}

// ---- fused attention L1 (HD=64): no-max softmax, 4 edges/wave, 16 lanes/edge,
// fp8 k (4B/lane) + bf16 v (8B/lane), depth-3 software pipeline ----
__global__ void k_attn1(const int* __restrict__ rowptr, const int* __restrict__ es,
                        const u16* __restrict__ q1b, const u16* __restrict__ kv1m,
                        const u16* __restrict__ s1b, u16* __restrict__ h1b) {
    int w = (blockIdx.x * blockDim.x + threadIdx.x) >> 6;
    if (w >= NN) return;
    int lane = threadIdx.x & 63;
    int g = lane >> 4, hl = lane & 15;  // edge-group, lane-in-group (dims 4hl..4hl+3)
    const float scale = 0.17677669529663687f;  // 1/sqrt(32)
    uint2 qu = ((const uint2*)(q1b + (size_t)w * 64))[hl];
    float qs0 = blo(qu.x) * scale, qs1 = bhi(qu.x) * scale;
    float qs2 = blo(qu.y) * scale, qs3 = bhi(qu.y) * scale;
    float l = 0.0f, o0 = 0.0f, o1 = 0.0f, o2 = 0.0f, o3 = 0.0f;
    int beg = rowptr[w], end = rowptr[w + 1];
    int iters = (end - beg + 3) >> 2;
#define PROC1(ku, vu, vld) { \
    f32x2 k01 = __builtin_amdgcn_cvt_pk_f32_fp8((int)ku, false); \
    f32x2 k23 = __builtin_amdgcn_cvt_pk_f32_fp8((int)ku, true); \
    float t = qs0 * k01.x + qs1 * k01.y + qs2 * k23.x + qs3 * k23.y; \
    t += __shfl_xor(t, 4, 64); t += __shfl_xor(t, 2, 64); t += __shfl_xor(t, 1, 64); \
    float e = (vld) ? __expf(t) : 0.0f; \
    l += e; \
    o0 += e * blo(vu.x); o1 += e * bhi(vu.x); \
    o2 += e * blo(vu.y); o3 += e * bhi(vu.y); }
    if (iters > 0) {
        int pA = beg + g;
        int vA = pA < end; int sjA = es[vA ? pA : beg];
        u32 kA = *(const u32*)(kv1m + (size_t)sjA * 96 + hl * 2);
        uint2 uA = *(const uint2*)(kv1m + (size_t)sjA * 96 + 32 + hl * 4);
        int pB = pA + 4;
        int vB = pB < end; int sjB = es[vB ? pB : beg];
        u32 kB = *(const u32*)(kv1m + (size_t)sjB * 96 + hl * 2);
        uint2 uB = *(const uint2*)(kv1m + (size_t)sjB * 96 + 32 + hl * 4);
        int pC = pA + 8;
        int vC = pC < end; int sjC = es[vC ? pC : beg];
        u32 kC = *(const u32*)(kv1m + (size_t)sjC * 96 + hl * 2);
        uint2 uC = *(const uint2*)(kv1m + (size_t)sjC * 96 + 32 + hl * 4);
        for (int i = 0; i < iters; i += 3) {
            int pD = pA + 12;
            int vD = pD < end; int sjD = es[vD ? pD : beg];
            u32 kD = *(const u32*)(kv1m + (size_t)sjD * 96 + hl * 2);
            uint2 uD = *(const uint2*)(kv1m + (size_t)sjD * 96 + 32 + hl * 4);
            PROC1(kA, uA, vA);
            int pE = pA + 16;
            int vE = pE < end; int sjE = es[vE ? pE : beg];
            u32 kE = *(const u32*)(kv1m + (size_t)sjE * 96 + hl * 2);
            uint2 uE = *(const uint2*)(kv1m + (size_t)sjE * 96 + 32 + hl * 4);
            PROC1(kB, uB, vB);
            int pF = pA + 20;
            int vF = pF < end; int sjF = es[vF ? pF : beg];
            u32 kF = *(const u32*)(kv1m + (size_t)sjF * 96 + hl * 2);
            uint2 uF = *(const uint2*)(kv1m + (size_t)sjF * 96 + 32 + hl * 4);
            PROC1(kC, uC, vC);
            pA = pD; vA = vD; kA = kD; uA = uD;
            pB = pE; vB = vE; kB = kE; uB = uE;
            pC = pF; vC = vF; kC = kF; uC = uF;
        }
    }
#undef PROC1
#pragma unroll
    for (int off = 16; off <= 32; off <<= 1) {
        l += __shfl_xor(l, off, 64);
        o0 += __shfl_xor(o0, off, 64);
        o1 += __shfl_xor(o1, off, 64);
        o2 += __shfl_xor(o2, off, 64);
        o3 += __shfl_xor(o3, off, 64);
    }
    if (g == 0) {
        float inv = 1.0f / (l + 1e-16f);
        uint2 su = ((const uint2*)(s1b + (size_t)w * 64))[hl];
        uint2 r;
        r.x = (u32)f2bu(fmaxf(blo(su.x) + o0 * inv, 0.0f)) | ((u32)f2bu(fmaxf(bhi(su.x) + o1 * inv, 0.0f)) << 16);
        r.y = (u32)f2bu(fmaxf(blo(su.y) + o2 * inv, 0.0f)) | ((u32)f2bu(fmaxf(bhi(su.y) + o3 * inv, 0.0f)) << 16);
        ((uint2*)(h1b + (size_t)w * 64))[hl] = r;
    }
}

// ---- weight prep for layer2 GEMM: Wt[512][64] bf16, bias512 f32; also zeroes g ----
__global__ void k_wprep(const void* __restrict__ Wq, const void* __restrict__ bq,
                        const void* __restrict__ Wk, const void* __restrict__ bk,
                        const void* __restrict__ Wv, const void* __restrict__ bv,
                        const void* __restrict__ Ws, const void* __restrict__ bs,
                        const int* __restrict__ flags,
                        u16* __restrict__ Wt, float* __restrict__ bias,
                        float* __restrict__ g) {
    int idx = blockIdx.x * blockDim.x + threadIdx.x;
    if (idx >= 512 * 64) return;
    if (idx < NG * 128) g[idx] = 0.0f;
    int fb = flags[2];
    int n = idx >> 6, k = idx & 63;
    int mat = n >> 7, c = n & 127;
    const void* W = (mat == 0) ? Wq : (mat == 1) ? Wk : (mat == 2) ? Wv : Ws;
    Wt[n * 64 + k] = f2bu(ldf(W, k * 128 + c, fb));
    if (k == 0) {
        const void* B = (mat == 0) ? bq : (mat == 1) ? bk : (mat == 2) ? bv : bs;
        bias[n] = ldf(B, c, fb);
    }
}

// ---- layer2 QKVS via MFMA; Q bf16, K fp8-e4m3 + V bf16 packed kvm[n]{128B k8|256B v}, S bf16 ----
__global__ void k_gemm2(const u16* __restrict__ h1b, const u16* __restrict__ Wt,
                        const float* __restrict__ bias,
                        u16* __restrict__ q2b, u16* __restrict__ kvm,
                        u16* __restrict__ s2b) {
    int w = (blockIdx.x * blockDim.x + threadIdx.x) >> 6;
    if (w >= NN / 16) return;  // 6250 waves
    int lane = threadIdx.x & 63;
    int quad = lane >> 4, mr = lane & 15;
    int m0 = w * 16;
    const u16* arow = h1b + (size_t)(m0 + mr) * 64 + quad * 8;
    bf16x8 a0 = *(const bf16x8*)(arow);
    bf16x8 a1 = *(const bf16x8*)(arow + 32);
#pragma unroll 4
    for (int n0 = 0; n0 < 512; n0 += 16) {
        const u16* brow = Wt + (size_t)(n0 + mr) * 64 + quad * 8;
        bf16x8 b0 = *(const bf16x8*)(brow);
        bf16x8 b1 = *(const bf16x8*)(brow + 32);
        f32x4 acc = {0.f, 0.f, 0.f, 0.f};
        acc = __builtin_amdgcn_mfma_f32_16x16x32_bf16(a0, b0, acc, 0, 0, 0);
        acc = __builtin_amdgcn_mfma_f32_16x16x32_bf16(a1, b1, acc, 0, 0, 0);
        float bs = bias[n0 + mr];
        int mat = n0 >> 7;
        int c = (n0 & 127) + mr;
#pragma unroll
        for (int r = 0; r < 4; r++) {
            int row = m0 + quad * 4 + r;
            float val = acc[r] + bs;
            if (mat == 1) {
                // fp8 k: pack column pairs across adjacent lanes (same row)
                float nb = __shfl_xor(val, 1, 64);
                if (!(mr & 1)) {
                    int packed = __builtin_amdgcn_cvt_pk_fp8_f32(val, nb, 0, false);
                    *(u16*)((char*)kvm + (size_t)row * 384 + c) = (u16)packed;
                }
            } else if (mat == 0) {
                q2b[(size_t)row * 128 + c] = f2bu(val);
            } else if (mat == 2) {
                kvm[(size_t)row * 192 + 64 + c] = f2bu(val);
            } else {
                s2b[(size_t)row * 128 + c] = f2bu(val);
            }
        }
    }
}

// ---- fused attention L2 (HD=128): no-max softmax, 4 edges/wave, 16 lanes/edge,
// fp8 k (8B/lane) + bf16 v (16B/lane), depth-3 software pipeline; h2 out bf16 ----
__global__ void k_attn2(const int* __restrict__ rowptr, const int* __restrict__ es,
                        const u16* __restrict__ q2b, const u16* __restrict__ kvm,
                        const u16* __restrict__ s2b, u16* __restrict__ h2b) {
    int w = (blockIdx.x * blockDim.x + threadIdx.x) >> 6;
    if (w >= NN) return;
    int lane = threadIdx.x & 63;
    int g = lane >> 4, hl = lane & 15;  // dims 8hl..8hl+7
    const float scale = 0.125f;  // 1/sqrt(64)
    uint4 qu = ((const uint4*)(q2b + (size_t)w * 128))[hl];
    float qs[8];
    qs[0] = blo(qu.x) * scale; qs[1] = bhi(qu.x) * scale;
    qs[2] = blo(qu.y) * scale; qs[3] = bhi(qu.y) * scale;
    qs[4] = blo(qu.z) * scale; qs[5] = bhi(qu.z) * scale;
    qs[6] = blo(qu.w) * scale; qs[7] = bhi(qu.w) * scale;
    float l = 0.0f;
    float o[8] = {0.f, 0.f, 0.f, 0.f, 0.f, 0.f, 0.f, 0.f};
    int beg = rowptr[w], end = rowptr[w + 1];
    int iters = (end - beg + 3) >> 2;
#define PROC2(ku, vu, vld) { \
    f32x2 k01 = __builtin_amdgcn_cvt_pk_f32_fp8((int)ku.x, false); \
    f32x2 k23 = __builtin_amdgcn_cvt_pk_f32_fp8((int)ku.x, true); \
    f32x2 k45 = __builtin_amdgcn_cvt_pk_f32_fp8((int)ku.y, false); \
    f32x2 k67 = __builtin_amdgcn_cvt_pk_f32_fp8((int)ku.y, true); \
    float t = qs[0] * k01.x + qs[1] * k01.y + qs[2] * k23.x + qs[3] * k23.y \
            + qs[4] * k45.x + qs[5] * k45.y + qs[6] * k67.x + qs[7] * k67.y; \
    t += __shfl_xor(t, 4, 64); t += __shfl_xor(t, 2, 64); t += __shfl_xor(t, 1, 64); \
    float e = (vld) ? __expf(t) : 0.0f; \
    l += e; \
    o[0] += e * blo(vu.x); o[1] += e * bhi(vu.x); \
    o[2] += e * blo(vu.y); o[3] += e * bhi(vu.y); \
    o[4] += e * blo(vu.z); o[5] += e * bhi(vu.z); \
    o[6] += e * blo(vu.w); o[7] += e * bhi(vu.w); }
    if (iters > 0) {
        int pA = beg + g;
        int vA = pA < end; int sjA = es[vA ? pA : beg];
        uint2 kA = ((const uint2*)(kvm + (size_t)sjA * 192))[hl];
        uint4 uA = ((const uint4*)(kvm + (size_t)sjA * 192 + 64))[hl];
        int pB = pA + 4;
        int vB = pB < end; int sjB = es[vB ? pB : beg];
        uint2 kB = ((const uint2*)(kvm + (size_t)sjB * 192))[hl];
        uint4 uB = ((const uint4*)(kvm + (size_t)sjB * 192 + 64))[hl];
        int pC = pA + 8;
        int vC = pC < end; int sjC = es[vC ? pC : beg];
        uint2 kC = ((const uint2*)(kvm + (size_t)sjC * 192))[hl];
        uint4 uC = ((const uint4*)(kvm + (size_t)sjC * 192 + 64))[hl];
        for (int i = 0; i < iters; i += 3) {
            int pD = pA + 12;
            int vD = pD < end; int sjD = es[vD ? pD : beg];
            uint2 kD = ((const uint2*)(kvm + (size_t)sjD * 192))[hl];
            uint4 uD = ((const uint4*)(kvm + (size_t)sjD * 192 + 64))[hl];
            PROC2(kA, uA, vA);
            int pE = pA + 16;
            int vE = pE < end; int sjE = es[vE ? pE : beg];
            uint2 kE = ((const uint2*)(kvm + (size_t)sjE * 192))[hl];
            uint4 uE = ((const uint4*)(kvm + (size_t)sjE * 192 + 64))[hl];
            PROC2(kB, uB, vB);
            int pF = pA + 20;
            int vF = pF < end; int sjF = es[vF ? pF : beg];
            uint2 kF = ((const uint2*)(kvm + (size_t)sjF * 192))[hl];
            uint4 uF = ((const uint4*)(kvm + (size_t)sjF * 192 + 64))[hl];
            PROC2(kC, uC, vC);
            pA = pD; vA = vD; kA = kD; uA = uD;
            pB = pE; vB = vE; kB = kE; uB = uE;
            pC = pF; vC = vF; kC = kF; uC = uF;
        }
    }
#undef PROC2
#pragma unroll
    for (int off = 16; off <= 32; off <<= 1) {
        l += __shfl_xor(l, off, 64);
#pragma unroll
        for (int j = 0; j < 8; j++) o[j] += __shfl_xor(o[j], off, 64);
    }
    if (g == 0) {
        float inv = 1.0f / (l + 1e-16f);
        uint4 su = ((const uint4*)(s2b + (size_t)w * 128))[hl];
        uint4 r;
        r.x = (u32)f2bu(blo(su.x) + o[0] * inv) | ((u32)f2bu(bhi(su.x) + o[1] * inv) << 16);
        r.y = (u32)f2bu(blo(su.y) + o[2] * inv) | ((u32)f2bu(bhi(su.y) + o[3] * inv) << 16);
        r.z = (u32)f2bu(blo(su.z) + o[4] * inv) | ((u32)f2bu(bhi(su.z) + o[5] * inv) << 16);
        r.w = (u32)f2bu(blo(su.w) + o[6] * inv) | ((u32)f2bu(bhi(su.w) + o[7] * inv) << 16);
        ((uint4*)(h2b + (size_t)w * 128))[hl] = r;
    }
}

// ---- relu + global max pool over sorted batch (pre-reduced runs: ~0.8M atomics) ----
__global__ void k_pool(const u16* __restrict__ h2b, const int* __restrict__ batch,
                       const int* __restrict__ flags, float* __restrict__ g) {
    int idx = blockIdx.x * blockDim.x + threadIdx.x;
    if (idx >= (NN / 16) * 128) return;
    int is64 = flags[1];
    int d = idx & 127, ch = idx >> 7;
    int n0 = ch * 16;
    int curb = ld_idx(batch, n0, is64);
    float mx = 0.0f;  // relu floor
    for (int i = 0; i < 16; i++) {
        int n = n0 + i;
        int b = ld_idx(batch, n, is64);
        if (b != curb) {
            atomicMax((int*)&g[curb * 128 + d], __float_as_int(mx));
            mx = 0.0f;
            curb = b;
        }
        mx = fmaxf(mx, __uint_as_float(((u32)h2b[(size_t)n * 128 + d]) << 16));
    }
    atomicMax((int*)&g[curb * 128 + d], __float_as_int(mx));
}

// ---- MLP head: one block per graph; f32 outputs ----
__global__ void k_mlp(const float* __restrict__ g,
                      const void* __restrict__ W1, const void* __restrict__ b1,
                      const void* __restrict__ W2, const void* __restrict__ b2,
                      const void* __restrict__ W3, const void* __restrict__ b3,
                      const int* __restrict__ flags, float* __restrict__ out) {
    __shared__ float gr[128], lat[32], h2[128];
    int gid = blockIdx.x, t = threadIdx.x;  // 128 threads
    int fb = flags[2];
    gr[t] = g[gid * 128 + t];
    __syncthreads();
    if (t < 32) {
        float a = ldf(b1, t, fb);
        for (int k = 0; k < 128; k++) a += gr[k] * ldf(W1, k * 32 + t, fb);
        a = fmaxf(a, 0.0f);
        lat[t] = a;
        out[NG * 40 + gid * 32 + t] = a;
    }
    __syncthreads();
    {
        float a = ldf(b2, t, fb);
        for (int k = 0; k < 32; k++) a += lat[k] * ldf(W2, k * 128 + t, fb);
        h2[t] = fmaxf(a, 0.0f);
    }
    __syncthreads();
    if (t < 40) {
        float a = ldf(b3, t, fb);
        for (int k = 0; k < 128; k++) a += h2[k] * ldf(W3, k * 40 + t, fb);
        out[gid * 40 + t] = a;
    }
}

extern "C" void kernel_launch(void* const* d_in, const int* in_sizes, int n_in,
                              void* d_out, int out_size, void* d_ws, size_t ws_size,
                              hipStream_t stream) {
    const void* x     = d_in[0];
    const int*  ei    = (const int*)d_in[1];
    const int*  batch = (const int*)d_in[2];
    const void *Wq1 = d_in[3],  *bq1 = d_in[4];
    const void *Wk1 = d_in[5],  *bk1 = d_in[6];
    const void *Wv1 = d_in[7],  *bv1 = d_in[8];
    const void *Ws1 = d_in[9],  *bs1 = d_in[10];
    const void *Wq2 = d_in[11], *bq2 = d_in[12];
    const void *Wk2 = d_in[13], *bk2 = d_in[14];
    const void *Wv2 = d_in[15], *bv2 = d_in[16];
    const void *Ws2 = d_in[17], *bs2 = d_in[18];
    const void *W1  = d_in[19], *b1  = d_in[20];
    const void *W2  = d_in[21], *b2  = d_in[22];
    const void *W3  = d_in[23], *b3  = d_in[24];

    // ---- workspace layout ----
    float* ws = (float*)d_ws;
    float* g    = ws;                                   // [64,128] f32
    float* bias = g + NG * 128;                         // [512] f32
    u16* u16base = (u16*)(bias + 512);
    u16* kvm   = u16base;                               // [N,192] u16: 128B k-fp8 | 256B v-bf16
    u16* kv1m  = kvm + (size_t)NN * 192;                // [N,96]  u16: 64B k-fp8 | 128B v-bf16
    u16* h1b   = kv1m + (size_t)NN * 96;                // [N,64]  bf16
    u16* q1b   = h1b + (size_t)NN * 64;                 // [N,64]  bf16
    u16* s1b   = q1b + (size_t)NN * 64;                 // [N,64]  bf16
    u16* q2b   = s1b + (size_t)NN * 64;                 // [N,128] bf16
    u16* s2b   = q2b + (size_t)NN * 128;                // [N,128] bf16
    u16* h2b   = s2b + (size_t)NN * 128;                // [N,128] bf16
    u16* Wt    = h2b + (size_t)NN * 128;                // [512,64] bf16
    int* flags  = (int*)(Wt + 512 * 64);                // [8]
    int* rowptr = flags + 8;                            // [NN+1]
    int* bhistT = rowptr + NN + 1;                      // [NBKT*NBLK]
    int* boffT  = bhistT + NBKT * NBLK;                 // [NBKT*NBLK]
    int* btot   = boffT + NBKT * NBLK;                  // [NBKT]
    int* bbase  = btot + NBKT;                          // [NBKT+1]
    int* es     = bbase + NBKT + 1;                     // [NE]
    // pairs aliases kvm (dead-time disjoint: CSR build finishes before gemm2 writes kvm)
    u32* pairs = (u32*)kvm;                             // [NE] = 6.4 MB <= 38.4 MB

    float* out  = (float*)d_out;

    const int B = 256;
    k_detect<<<1, 256, 0, stream>>>(ei, batch, (const u16*)x, flags);
    // ---- CSR build: bucketed counting sort (no global atomics, fully parallel scan) ----
    k_p1hist<<<NBLK, 512, 0, stream>>>(ei, flags, bhistT);
    k_p2a<<<NBKT, 512, 0, stream>>>(bhistT, boffT, btot);
    k_p2b<<<1, 256, 0, stream>>>(btot, bbase);
    k_p3part<<<NBLK, 512, 0, stream>>>(ei, flags, boffT, bbase, pairs);
    k_p4sort<<<NBKT, 512, 0, stream>>>(pairs, bbase, rowptr, es);
    // ---- layer 1 ----
    k_qkvs1<<<(NN * 64 + B - 1) / B, B, 0, stream>>>(x, Wq1, bq1, Wk1, bk1, Wv1, bv1, Ws1, bs1,
                                                     flags, q1b, kv1m, s1b);
    k_attn1<<<(NN * 64 + B - 1) / B, B, 0, stream>>>(rowptr, es, q1b, kv1m, s1b, h1b);
    // ---- layer 2 ----
    k_wprep<<<(512 * 64 + B - 1) / B, B, 0, stream>>>(Wq2, bq2, Wk2, bk2, Wv2, bv2, Ws2, bs2,
                                                      flags, Wt, bias, g);
    k_gemm2<<<(NN / 16 * 64 + B - 1) / B, B, 0, stream>>>(h1b, Wt, bias, q2b, kvm, s2b);
    k_attn2<<<(NN * 64 + B - 1) / B, B, 0, stream>>>(rowptr, es, q2b, kvm, s2b, h2b);
    // ---- pool + MLP ----
    k_pool<<<((NN / 16) * 128 + B - 1) / B, B, 0, stream>>>(h2b, batch, flags, g);
    k_mlp<<<NG, 128, 0, stream>>>(g, W1, b1, W2, b2, W3, b3, flags, out);
}